// Round 5
// baseline (255.765 us; speedup 1.0000x reference)
//
#include <hip/hip_runtime.h>

// GaussianRecuModel: B=512 batches, T=8192-step affine recurrence on 2-state x.
//   x_{t+1} = Mt x_t + bt,  Mt = I + dt*A - dt*(xic_t C),  bt = xic_t dy_t
//   out_t   = dt * C x_t   (state BEFORE update)
//
// R5: chained single-pass scan. 2048 blocks x 256 threads; each block owns a
// 2048-step chunk (4 chunks/batch), 8 blocks/CU co-resident (16 KiB LDS) so
// load/compute phases of different blocks overlap. Cross-chunk state handoff
// via agent-scope atomics (chained scan, ticket-ordered => deadlock-free).

#define B_    512
#define T_    8192
#define LPT   8                  // steps per thread
#define NT    256                // threads per block (4 waves)
#define CSTEP (NT * LPT)         // 2048 steps per block
#define NCHK  (T_ / CSTEP)       // 4 chunks per batch
#define NBLK  (B_ * NCHK)        // 2048 blocks

struct Aff { float m00, m01, m10, m11, v0, v1; };

__device__ __forceinline__ Aff aff_compose(const Aff& L, const Aff& E) {
    Aff r;
    r.m00 = L.m00*E.m00 + L.m01*E.m10;
    r.m01 = L.m00*E.m01 + L.m01*E.m11;
    r.m10 = L.m10*E.m00 + L.m11*E.m10;
    r.m11 = L.m10*E.m01 + L.m11*E.m11;
    r.v0  = L.m00*E.v0  + L.m01*E.v1 + L.v0;
    r.v1  = L.m10*E.v0  + L.m11*E.v1 + L.v1;
    return r;
}

__device__ __forceinline__ Aff aff_identity() {
    Aff r; r.m00 = 1.f; r.m01 = 0.f; r.m10 = 0.f; r.m11 = 1.f; r.v0 = 0.f; r.v1 = 0.f;
    return r;
}

__global__ __launch_bounds__(NT) void grm_chain(
    const float* __restrict__ xic, const float* __restrict__ dy,
    const float* __restrict__ Aptr, const float* __restrict__ Cptr,
    float4* __restrict__ out4,
    unsigned* __restrict__ ticket, unsigned* __restrict__ flags,
    float* __restrict__ vals)
{
    __shared__ float4 lds4[4 * 256];   // 4 waves x 4 KiB slices
    __shared__ float  xin_s[2];
    __shared__ int    vid_s;

    const int tid  = threadIdx.x;
    const int lane = tid & 63;
    const int wave = tid >> 6;

    if (tid == 0) vid_s = (int)atomicAdd(ticket, 1u);
    __syncthreads();
    const int vid = vid_s;
    const int b   = vid >> 2;          // batch
    const int c   = vid & (NCHK - 1);  // chunk within batch

    float4* slice = lds4 + wave * 256;

    const float DT = 1e-3f;
    const float cd00 = Cptr[0]*DT, cd01 = Cptr[1]*DT;
    const float cd10 = Cptr[2]*DT, cd11 = Cptr[3]*DT;
    const float i00 = 1.0f + Aptr[0]*DT, i01 = Aptr[1]*DT;
    const float i10 = Aptr[2]*DT,        i11 = 1.0f + Aptr[3]*DT;

    // wave covers 512 consecutive steps
    const int wbase = b * T_ + c * CSTEP + wave * 512;      // step index
    const float4* xw = (const float4*)xic + wbase;          // 512 f4 / wave
    const float4* dw = (const float4*)dy  + (wbase >> 1);   // 256 f4 / wave
    float4*       ow = out4 + (wbase >> 1);                 // 256 f4 / wave

    // ---- coalesced global loads ----
    float4 t[8], u[4];
    #pragma unroll
    for (int j = 0; j < 8; ++j) t[j] = xw[j*64 + lane];
    #pragma unroll
    for (int j = 0; j < 4; ++j) u[j] = dw[j*64 + lane];

    // ---- xic transpose (wave-private slice, 2 owner-rounds) ----
    // owner o = f>>3, slot = f&7; addr = rel*8 + (slot ^ (rel&7)), rel=o&31
    float4 a[LPT];
    #pragma unroll
    for (int rr = 0; rr < 2; ++rr) {
        #pragma unroll
        for (int jj = 0; jj < 4; ++jj) {
            int j = 4*rr + jj;
            int f = j*64 + lane;
            int rel = (f >> 3) & 31;
            slice[rel*8 + ((lane & 7) ^ (rel & 7))] = t[j];
        }
        if ((lane >> 5) == rr) {
            int rel = lane & 31;
            #pragma unroll
            for (int s = 0; s < LPT; ++s)
                a[s] = slice[rel*8 + (s ^ (rel & 7))];
        }
    }

    // ---- dy transpose: owner o = f>>2, slot = f&3; swz(o) = (o>>1)&3 ----
    #pragma unroll
    for (int j = 0; j < 4; ++j) {
        int f = j*64 + lane;
        int o = f >> 2;
        slice[o*4 + ((f & 3) ^ ((o >> 1) & 3))] = u[j];
    }
    float4 d[4];
    #pragma unroll
    for (int s = 0; s < 4; ++s)
        d[s] = slice[lane*4 + (s ^ ((lane >> 1) & 3))];

#define STEP_MAP(i, S)                                                  \
    {                                                                   \
        const float4 x4 = a[i];                                         \
        const float dyx = ((i)&1) ? d[(i)>>1].z : d[(i)>>1].x;          \
        const float dyy = ((i)&1) ? d[(i)>>1].w : d[(i)>>1].y;          \
        (S).m00 = i00 - (x4.x*cd00 + x4.y*cd10);                        \
        (S).m01 = i01 - (x4.x*cd01 + x4.y*cd11);                        \
        (S).m10 = i10 - (x4.z*cd00 + x4.w*cd10);                        \
        (S).m11 = i11 - (x4.z*cd01 + x4.w*cd11);                        \
        (S).v0  = x4.x*dyx + x4.y*dyy;                                  \
        (S).v1  = x4.z*dyx + x4.w*dyy;                                  \
    }

    // ---- thread-local compose ----
    Aff P;
    STEP_MAP(0, P);
    #pragma unroll
    for (int i = 1; i < LPT; ++i) { Aff s; STEP_MAP(i, s); P = aff_compose(s, P); }

    // ---- wave Kogge-Stone inclusive scan ----
    Aff S = P;
    #pragma unroll
    for (int sh = 1; sh < 64; sh <<= 1) {
        Aff q;
        q.m00 = __shfl_up(S.m00, sh); q.m01 = __shfl_up(S.m01, sh);
        q.m10 = __shfl_up(S.m10, sh); q.m11 = __shfl_up(S.m11, sh);
        q.v0  = __shfl_up(S.v0,  sh); q.v1  = __shfl_up(S.v1,  sh);
        if (lane >= sh) S = aff_compose(S, q);
    }

    // ---- wave totals -> slice headers ----
    if (lane == 63) {
        float* h = (float*)slice;
        h[0] = S.m00; h[1] = S.m01; h[2] = S.m10; h[3] = S.m11;
        h[4] = S.v0;  h[5] = S.v1;
    }
    __syncthreads();

    // ---- per-thread wave-exclusive prefix (<=3 composes) ----
    Aff Ew = aff_identity();
    for (int w = 0; w < wave; ++w) {
        const float* h = (const float*)(lds4 + w * 256);
        Aff t2;
        t2.m00 = h[0]; t2.m01 = h[1]; t2.m10 = h[2]; t2.m11 = h[3];
        t2.v0  = h[4]; t2.v1  = h[5];
        Ew = aff_compose(t2, Ew);
    }

    // ---- thread 0: block total, chain handoff ----
    if (tid == 0) {
        Aff Tb = aff_identity();
        #pragma unroll
        for (int w = 0; w < 4; ++w) {
            const float* h = (const float*)(lds4 + w * 256);
            Aff t2;
            t2.m00 = h[0]; t2.m01 = h[1]; t2.m10 = h[2]; t2.m11 = h[3];
            t2.v0  = h[4]; t2.v1  = h[5];
            Tb = aff_compose(t2, Tb);
        }
        float x0, x1;
        if (c == 0) {
            x0 = 1.0f; x1 = 0.0f;
        } else {
            const int p = vid - 1;
            while (__hip_atomic_load(&flags[p], __ATOMIC_ACQUIRE,
                                     __HIP_MEMORY_SCOPE_AGENT) == 0u)
                __builtin_amdgcn_s_sleep(4);
            x0 = __hip_atomic_load(&vals[2*p],   __ATOMIC_RELAXED, __HIP_MEMORY_SCOPE_AGENT);
            x1 = __hip_atomic_load(&vals[2*p+1], __ATOMIC_RELAXED, __HIP_MEMORY_SCOPE_AGENT);
        }
        if (c < NCHK - 1) {
            float y0 = Tb.m00*x0 + Tb.m01*x1 + Tb.v0;
            float y1 = Tb.m10*x0 + Tb.m11*x1 + Tb.v1;
            __hip_atomic_store(&vals[2*vid],   y0, __ATOMIC_RELAXED, __HIP_MEMORY_SCOPE_AGENT);
            __hip_atomic_store(&vals[2*vid+1], y1, __ATOMIC_RELAXED, __HIP_MEMORY_SCOPE_AGENT);
            __hip_atomic_store(&flags[vid], 1u, __ATOMIC_RELEASE, __HIP_MEMORY_SCOPE_AGENT);
        }
        xin_s[0] = x0; xin_s[1] = x1;
    }

    // ---- lane-exclusive prefix within wave ----
    Aff El;
    El.m00 = __shfl_up(S.m00, 1); El.m01 = __shfl_up(S.m01, 1);
    El.m10 = __shfl_up(S.m10, 1); El.m11 = __shfl_up(S.m11, 1);
    El.v0  = __shfl_up(S.v0,  1); El.v1  = __shfl_up(S.v1,  1);
    if (lane == 0) El = aff_identity();
    Aff E = aff_compose(El, Ew);     // exclusive prefix within block

    __syncthreads();                 // xin_s ready; headers consumed
    float xb0 = xin_s[0], xb1 = xin_s[1];
    float x0 = E.m00*xb0 + E.m01*xb1 + E.v0;
    float x1 = E.m10*xb0 + E.m11*xb1 + E.v1;

    // ---- replay from registers ----
    float4 o4[4];
    #pragma unroll
    for (int i = 0; i < LPT; ++i) {
        float oxx = cd00*x0 + cd01*x1;
        float oyy = cd10*x0 + cd11*x1;
        if (i & 1) { o4[i>>1].z = oxx; o4[i>>1].w = oyy; }
        else       { o4[i>>1].x = oxx; o4[i>>1].y = oyy; }
        Aff s; STEP_MAP(i, s);
        float nx0 = s.m00*x0 + s.m01*x1 + s.v0;
        float nx1 = s.m10*x0 + s.m11*x1 + s.v1;
        x0 = nx0; x1 = nx1;
    }
#undef STEP_MAP

    // ---- out transpose (same swizzle as dy), coalesced stores ----
    #pragma unroll
    for (int s = 0; s < 4; ++s)
        slice[lane*4 + (s ^ ((lane >> 1) & 3))] = o4[s];
    #pragma unroll
    for (int j = 0; j < 4; ++j) {
        int f = j*64 + lane;
        int o = f >> 2;
        ow[f] = slice[o*4 + ((f & 3) ^ ((o >> 1) & 3))];
    }
}

extern "C" void kernel_launch(void* const* d_in, const int* in_sizes, int n_in,
                              void* d_out, int out_size, void* d_ws, size_t ws_size,
                              hipStream_t stream) {
    const float* xic  = (const float*)d_in[0];   // [B,T,2,2]
    const float* dy   = (const float*)d_in[1];   // [B,T,2]
    const float* Aptr = (const float*)d_in[2];   // [2,2]
    const float* Cptr = (const float*)d_in[3];   // [2,2]
    float4* out = (float4*)d_out;                // [B,T,2]

    // ws layout:
    //   [0,4)            ticket counter
    //   [256, 256+8K)    flags  (NBLK u32)
    //   [16K, 16K+16K)   vals   (NBLK x 2 floats)  -- no init needed
    char* ws = (char*)d_ws;
    unsigned* ticket = (unsigned*)ws;
    unsigned* flags  = (unsigned*)(ws + 256);
    float*    vals   = (float*)(ws + 16384);

    hipMemsetAsync(ws, 0, 256 + NBLK * sizeof(unsigned), stream);
    grm_chain<<<NBLK, NT, 0, stream>>>(xic, dy, Aptr, Cptr, out,
                                       ticket, flags, vals);
}

// Round 7
// 150.055 us; speedup vs baseline: 1.7045x; 1.7045x over previous
//
#include <hip/hip_runtime.h>

// GaussianRecuModel: B=512 batches, T=8192-step affine recurrence on 2-state x.
//   x_{t+1} = Mt x_t + bt,  Mt = I + dt*A - dt*(xic_t C),  bt = xic_t dy_t
//   out_t   = dt * C x_t   (state BEFORE update)
//
// R7: three deterministic kernels, 256-thread blocks (8 blocks/CU).
//  K1 grm_tot : per-(batch,chunk) affine totals for chunks 0..2 -> ws.
//  K2 grm_xs  : 512 threads; EXACT sequential state propagation through the
//               chunk totals (same arithmetic as R5's proven chain) -> chunk
//               start states xs[b][c] in ws.
//  K3 grm_emit: read broadcast xs[b][c], in-block scan + replay + coalesced
//               stores. In-block machinery is VERBATIM R5 (proven 3.05e-5);
//               R6's helper-function + in-consumer matrix-composition carry
//               are both removed (R6 failed at 1.06e-3).

#define B_    512
#define T_    8192
#define LPT   8                  // steps per thread
#define NT    256                // threads per block (4 waves)
#define CSTEP (NT * LPT)         // 2048 steps per block
#define NCHK  (T_ / CSTEP)       // 4 chunks per batch

struct Aff { float m00, m01, m10, m11, v0, v1; };

__device__ __forceinline__ Aff aff_compose(const Aff& L, const Aff& E) {
    Aff r;
    r.m00 = L.m00*E.m00 + L.m01*E.m10;
    r.m01 = L.m00*E.m01 + L.m01*E.m11;
    r.m10 = L.m10*E.m00 + L.m11*E.m10;
    r.m11 = L.m10*E.m01 + L.m11*E.m11;
    r.v0  = L.m00*E.v0  + L.m01*E.v1 + L.v0;
    r.v1  = L.m10*E.v0  + L.m11*E.v1 + L.v1;
    return r;
}

__device__ __forceinline__ Aff aff_identity() {
    Aff r; r.m00 = 1.f; r.m01 = 0.f; r.m10 = 0.f; r.m11 = 1.f; r.v0 = 0.f; r.v1 = 0.f;
    return r;
}

// ============================ K1: chunk totals ============================
__global__ __launch_bounds__(NT) void grm_tot(
    const float* __restrict__ xic, const float* __restrict__ dy,
    const float* __restrict__ Aptr, const float* __restrict__ Cptr,
    float* __restrict__ totals)           // [B][3][6]
{
    __shared__ float4 lds4[4 * 256];   // 4 waves x 4 KiB slices

    const int blk  = blockIdx.x;       // 0..1535
    const int b    = blk / 3;
    const int c    = blk - b * 3;      // chunk 0..2
    const int tid  = threadIdx.x;
    const int lane = tid & 63;
    const int wave = tid >> 6;

    float4* slice = lds4 + wave * 256;

    const float DT = 1e-3f;
    const float cd00 = Cptr[0]*DT, cd01 = Cptr[1]*DT;
    const float cd10 = Cptr[2]*DT, cd11 = Cptr[3]*DT;
    const float i00 = 1.0f + Aptr[0]*DT, i01 = Aptr[1]*DT;
    const float i10 = Aptr[2]*DT,        i11 = 1.0f + Aptr[3]*DT;

    const int wbase = b * T_ + c * CSTEP + wave * 512;      // step index
    const float4* xw = (const float4*)xic + wbase;
    const float4* dw = (const float4*)dy  + (wbase >> 1);

    // ---- coalesced global loads ----
    float4 t[8], u[4];
    #pragma unroll
    for (int j = 0; j < 8; ++j) t[j] = xw[j*64 + lane];
    #pragma unroll
    for (int j = 0; j < 4; ++j) u[j] = dw[j*64 + lane];

    // ---- xic transpose (wave-private slice, 2 owner-rounds) ----
    float4 a[LPT];
    #pragma unroll
    for (int rr = 0; rr < 2; ++rr) {
        #pragma unroll
        for (int jj = 0; jj < 4; ++jj) {
            int j = 4*rr + jj;
            int f = j*64 + lane;
            int rel = (f >> 3) & 31;
            slice[rel*8 + ((lane & 7) ^ (rel & 7))] = t[j];
        }
        if ((lane >> 5) == rr) {
            int rel = lane & 31;
            #pragma unroll
            for (int s = 0; s < LPT; ++s)
                a[s] = slice[rel*8 + (s ^ (rel & 7))];
        }
    }

    // ---- dy transpose ----
    #pragma unroll
    for (int j = 0; j < 4; ++j) {
        int f = j*64 + lane;
        int o = f >> 2;
        slice[o*4 + ((f & 3) ^ ((o >> 1) & 3))] = u[j];
    }
    float4 d[4];
    #pragma unroll
    for (int s = 0; s < 4; ++s)
        d[s] = slice[lane*4 + (s ^ ((lane >> 1) & 3))];

#define STEP_MAPA(i, S_)                                                \
    {                                                                   \
        const float4 x4 = a[i];                                         \
        const float dyx = ((i)&1) ? d[(i)>>1].z : d[(i)>>1].x;          \
        const float dyy = ((i)&1) ? d[(i)>>1].w : d[(i)>>1].y;          \
        (S_).m00 = i00 - (x4.x*cd00 + x4.y*cd10);                       \
        (S_).m01 = i01 - (x4.x*cd01 + x4.y*cd11);                       \
        (S_).m10 = i10 - (x4.z*cd00 + x4.w*cd10);                       \
        (S_).m11 = i11 - (x4.z*cd01 + x4.w*cd11);                       \
        (S_).v0  = x4.x*dyx + x4.y*dyy;                                 \
        (S_).v1  = x4.z*dyx + x4.w*dyy;                                 \
    }

    // ---- thread-local compose ----
    Aff P;
    STEP_MAPA(0, P);
    #pragma unroll
    for (int i = 1; i < LPT; ++i) { Aff s; STEP_MAPA(i, s); P = aff_compose(s, P); }
#undef STEP_MAPA

    // ---- wave Kogge-Stone inclusive scan ----
    Aff S = P;
    #pragma unroll
    for (int sh = 1; sh < 64; sh <<= 1) {
        Aff q;
        q.m00 = __shfl_up(S.m00, sh); q.m01 = __shfl_up(S.m01, sh);
        q.m10 = __shfl_up(S.m10, sh); q.m11 = __shfl_up(S.m11, sh);
        q.v0  = __shfl_up(S.v0,  sh); q.v1  = __shfl_up(S.v1,  sh);
        if (lane >= sh) S = aff_compose(S, q);
    }

    // ---- wave totals -> slice headers ----
    if (lane == 63) {
        float* h = (float*)slice;
        h[0] = S.m00; h[1] = S.m01; h[2] = S.m10; h[3] = S.m11;
        h[4] = S.v0;  h[5] = S.v1;
    }
    __syncthreads();

    if (tid == 0) {
        Aff Tb = aff_identity();
        #pragma unroll
        for (int w = 0; w < 4; ++w) {
            const float* h = (const float*)(lds4 + w * 256);
            Aff t2;
            t2.m00 = h[0]; t2.m01 = h[1]; t2.m10 = h[2]; t2.m11 = h[3];
            t2.v0  = h[4]; t2.v1  = h[5];
            Tb = aff_compose(t2, Tb);
        }
        float* o = totals + (size_t)blk * 6;
        o[0] = Tb.m00; o[1] = Tb.m01; o[2] = Tb.m10; o[3] = Tb.m11;
        o[4] = Tb.v0;  o[5] = Tb.v1;
    }
}

// ==================== K2: sequential chunk-start states ====================
// Exact arithmetic of R5's proven chain: x <- M x + v per chunk.
__global__ __launch_bounds__(NT) void grm_xs(
    const float* __restrict__ totals,     // [B][3][6]
    float2* __restrict__ xs)              // [B][4]
{
    const int b = blockIdx.x * NT + threadIdx.x;   // 2 blocks x 256 = 512
    float x0 = 1.0f, x1 = 0.0f;
    float2* xb = xs + (size_t)b * NCHK;
    xb[0] = make_float2(x0, x1);
    for (int c = 0; c < NCHK - 1; ++c) {
        const float* h = totals + ((size_t)b * 3 + c) * 6;
        float nx0 = h[0]*x0 + h[1]*x1 + h[4];
        float nx1 = h[2]*x0 + h[3]*x1 + h[5];
        x0 = nx0; x1 = nx1;
        xb[c + 1] = make_float2(x0, x1);
    }
}

// ============================ K3: emit ============================
__global__ __launch_bounds__(NT) void grm_emit(
    const float* __restrict__ xic, const float* __restrict__ dy,
    const float* __restrict__ Aptr, const float* __restrict__ Cptr,
    const float2* __restrict__ xs,        // [B][4]
    float4* __restrict__ out4)
{
    __shared__ float4 lds4[4 * 256];

    const int blk  = blockIdx.x;          // 0..2047  = b*4 + c
    const int b    = blk >> 2;
    const int c    = blk & (NCHK - 1);
    const int tid  = threadIdx.x;
    const int lane = tid & 63;
    const int wave = tid >> 6;

    float4* slice = lds4 + wave * 256;

    const float DT = 1e-3f;
    const float cd00 = Cptr[0]*DT, cd01 = Cptr[1]*DT;
    const float cd10 = Cptr[2]*DT, cd11 = Cptr[3]*DT;
    const float i00 = 1.0f + Aptr[0]*DT, i01 = Aptr[1]*DT;
    const float i10 = Aptr[2]*DT,        i11 = 1.0f + Aptr[3]*DT;

    // carry-in state: single broadcast float2
    const float2 xbv = xs[blk];
    const float xb0 = xbv.x, xb1 = xbv.y;

    const int wbase = b * T_ + c * CSTEP + wave * 512;
    const float4* xw = (const float4*)xic + wbase;
    const float4* dw = (const float4*)dy  + (wbase >> 1);
    float4*       ow = out4 + (wbase >> 1);

    // ---- coalesced global loads ----
    float4 t[8], u[4];
    #pragma unroll
    for (int j = 0; j < 8; ++j) t[j] = xw[j*64 + lane];
    #pragma unroll
    for (int j = 0; j < 4; ++j) u[j] = dw[j*64 + lane];

    // ---- xic transpose ----
    float4 a[LPT];
    #pragma unroll
    for (int rr = 0; rr < 2; ++rr) {
        #pragma unroll
        for (int jj = 0; jj < 4; ++jj) {
            int j = 4*rr + jj;
            int f = j*64 + lane;
            int rel = (f >> 3) & 31;
            slice[rel*8 + ((lane & 7) ^ (rel & 7))] = t[j];
        }
        if ((lane >> 5) == rr) {
            int rel = lane & 31;
            #pragma unroll
            for (int s = 0; s < LPT; ++s)
                a[s] = slice[rel*8 + (s ^ (rel & 7))];
        }
    }

    // ---- dy transpose ----
    #pragma unroll
    for (int j = 0; j < 4; ++j) {
        int f = j*64 + lane;
        int o = f >> 2;
        slice[o*4 + ((f & 3) ^ ((o >> 1) & 3))] = u[j];
    }
    float4 d[4];
    #pragma unroll
    for (int s = 0; s < 4; ++s)
        d[s] = slice[lane*4 + (s ^ ((lane >> 1) & 3))];

#define STEP_MAPB(i, S_)                                                \
    {                                                                   \
        const float4 x4 = a[i];                                         \
        const float dyx = ((i)&1) ? d[(i)>>1].z : d[(i)>>1].x;          \
        const float dyy = ((i)&1) ? d[(i)>>1].w : d[(i)>>1].y;          \
        (S_).m00 = i00 - (x4.x*cd00 + x4.y*cd10);                       \
        (S_).m01 = i01 - (x4.x*cd01 + x4.y*cd11);                       \
        (S_).m10 = i10 - (x4.z*cd00 + x4.w*cd10);                       \
        (S_).m11 = i11 - (x4.z*cd01 + x4.w*cd11);                       \
        (S_).v0  = x4.x*dyx + x4.y*dyy;                                 \
        (S_).v1  = x4.z*dyx + x4.w*dyy;                                 \
    }

    // ---- thread-local compose ----
    Aff P;
    STEP_MAPB(0, P);
    #pragma unroll
    for (int i = 1; i < LPT; ++i) { Aff s; STEP_MAPB(i, s); P = aff_compose(s, P); }

    // ---- wave Kogge-Stone inclusive scan ----
    Aff S = P;
    #pragma unroll
    for (int sh = 1; sh < 64; sh <<= 1) {
        Aff q;
        q.m00 = __shfl_up(S.m00, sh); q.m01 = __shfl_up(S.m01, sh);
        q.m10 = __shfl_up(S.m10, sh); q.m11 = __shfl_up(S.m11, sh);
        q.v0  = __shfl_up(S.v0,  sh); q.v1  = __shfl_up(S.v1,  sh);
        if (lane >= sh) S = aff_compose(S, q);
    }

    // ---- wave totals -> slice headers ----
    if (lane == 63) {
        float* h = (float*)slice;
        h[0] = S.m00; h[1] = S.m01; h[2] = S.m10; h[3] = S.m11;
        h[4] = S.v0;  h[5] = S.v1;
    }
    __syncthreads();

    // ---- wave-exclusive prefix within block (<=3 composes) ----
    Aff Ew = aff_identity();
    for (int w = 0; w < wave; ++w) {
        const float* h = (const float*)(lds4 + w * 256);
        Aff t2;
        t2.m00 = h[0]; t2.m01 = h[1]; t2.m10 = h[2]; t2.m11 = h[3];
        t2.v0  = h[4]; t2.v1  = h[5];
        Ew = aff_compose(t2, Ew);
    }

    // ---- lane-exclusive prefix within wave ----
    Aff El;
    El.m00 = __shfl_up(S.m00, 1); El.m01 = __shfl_up(S.m01, 1);
    El.m10 = __shfl_up(S.m10, 1); El.m11 = __shfl_up(S.m11, 1);
    El.v0  = __shfl_up(S.v0,  1); El.v1  = __shfl_up(S.v1,  1);
    if (lane == 0) El = aff_identity();
    Aff E = aff_compose(El, Ew);     // exclusive prefix within block

    __syncthreads();                 // headers consumed; slices reusable

    float x0 = E.m00*xb0 + E.m01*xb1 + E.v0;
    float x1 = E.m10*xb0 + E.m11*xb1 + E.v1;

    // ---- replay from registers ----
    float4 o4[4];
    #pragma unroll
    for (int i = 0; i < LPT; ++i) {
        float oxx = cd00*x0 + cd01*x1;
        float oyy = cd10*x0 + cd11*x1;
        if (i & 1) { o4[i>>1].z = oxx; o4[i>>1].w = oyy; }
        else       { o4[i>>1].x = oxx; o4[i>>1].y = oyy; }
        Aff s; STEP_MAPB(i, s);
        float nx0 = s.m00*x0 + s.m01*x1 + s.v0;
        float nx1 = s.m10*x0 + s.m11*x1 + s.v1;
        x0 = nx0; x1 = nx1;
    }
#undef STEP_MAPB

    // ---- out transpose, coalesced stores ----
    #pragma unroll
    for (int s = 0; s < 4; ++s)
        slice[lane*4 + (s ^ ((lane >> 1) & 3))] = o4[s];
    #pragma unroll
    for (int j = 0; j < 4; ++j) {
        int f = j*64 + lane;
        int o = f >> 2;
        ow[f] = slice[o*4 + ((f & 3) ^ ((o >> 1) & 3))];
    }
}

extern "C" void kernel_launch(void* const* d_in, const int* in_sizes, int n_in,
                              void* d_out, int out_size, void* d_ws, size_t ws_size,
                              hipStream_t stream) {
    const float* xic  = (const float*)d_in[0];   // [B,T,2,2]
    const float* dy   = (const float*)d_in[1];   // [B,T,2]
    const float* Aptr = (const float*)d_in[2];   // [2,2]
    const float* Cptr = (const float*)d_in[3];   // [2,2]
    float4* out = (float4*)d_out;                // [B,T,2]

    // ws layout:
    //   [0, 36864)        totals  [B][3][6] float   (written fully by K1)
    //   [40960, 57344)    xs      [B][4]    float2  (written fully by K2)
    char* ws = (char*)d_ws;
    float*  totals = (float*)ws;
    float2* xs     = (float2*)(ws + 40960);

    grm_tot <<<B_ * 3,    NT, 0, stream>>>(xic, dy, Aptr, Cptr, totals);
    grm_xs  <<<B_ / NT,   NT, 0, stream>>>(totals, xs);
    grm_emit<<<B_ * NCHK, NT, 0, stream>>>(xic, dy, Aptr, Cptr, xs, out);
}

// Round 8
// 149.305 us; speedup vs baseline: 1.7130x; 1.0050x over previous
//
#include <hip/hip_runtime.h>
#include <hip/hip_cooperative_groups.h>

namespace cg = cooperative_groups;

// GaussianRecuModel: B=512 batches, T=8192-step affine recurrence on 2-state x.
//   x_{t+1} = Mt x_t + bt,  Mt = I + dt*A - dt*(xic_t C),  bt = xic_t dy_t
//   out_t   = dt * C x_t   (state BEFORE update)
//
// R8: single-pass cooperative kernel. 2048 blocks x 256 threads (8 blocks/CU,
// the full thread capacity), __launch_bounds__(256,8). Phase A composes
// per-chunk totals keeping xic in registers; grid.sync(); phase B resolves
// the carry with R7's proven sequential arithmetic, re-reads only dy
// (L3-warm), replays, stores coalesced. xic is read from memory ONCE.
// Fallback (occupancy < 8 blocks/CU): R7's proven 3-kernel path.

#define B_    512
#define T_    8192
#define LPT   8                  // steps per thread
#define NT    256                // threads per block (4 waves)
#define CSTEP (NT * LPT)         // 2048 steps per block
#define NCHK  (T_ / CSTEP)       // 4 chunks per batch
#define NBLK  (B_ * NCHK)        // 2048 blocks

struct Aff { float m00, m01, m10, m11, v0, v1; };

__device__ __forceinline__ Aff aff_compose(const Aff& L, const Aff& E) {
    Aff r;
    r.m00 = L.m00*E.m00 + L.m01*E.m10;
    r.m01 = L.m00*E.m01 + L.m01*E.m11;
    r.m10 = L.m10*E.m00 + L.m11*E.m10;
    r.m11 = L.m10*E.m01 + L.m11*E.m11;
    r.v0  = L.m00*E.v0  + L.m01*E.v1 + L.v0;
    r.v1  = L.m10*E.v0  + L.m11*E.v1 + L.v1;
    return r;
}

__device__ __forceinline__ Aff aff_identity() {
    Aff r; r.m00 = 1.f; r.m01 = 0.f; r.m10 = 0.f; r.m11 = 1.f; r.v0 = 0.f; r.v1 = 0.f;
    return r;
}

#define STEP_MAP(i, S_)                                                 \
    {                                                                   \
        const float4 x4 = a[i];                                         \
        const float dyx = ((i)&1) ? d[(i)>>1].z : d[(i)>>1].x;          \
        const float dyy = ((i)&1) ? d[(i)>>1].w : d[(i)>>1].y;          \
        (S_).m00 = i00 - (x4.x*cd00 + x4.y*cd10);                       \
        (S_).m01 = i01 - (x4.x*cd01 + x4.y*cd11);                       \
        (S_).m10 = i10 - (x4.z*cd00 + x4.w*cd10);                       \
        (S_).m11 = i11 - (x4.z*cd01 + x4.w*cd11);                       \
        (S_).v0  = x4.x*dyx + x4.y*dyy;                                 \
        (S_).v1  = x4.z*dyx + x4.w*dyy;                                 \
    }

// ======================= R8: cooperative single pass =======================
__global__ __launch_bounds__(NT, 8) void grm_coop(
    const float* __restrict__ xic, const float* __restrict__ dy,
    const float* __restrict__ Aptr, const float* __restrict__ Cptr,
    float* __restrict__ totals,           // [NBLK][6]
    float4* __restrict__ out4)
{
    __shared__ float4 lds4[4 * 256];   // 4 waves x 4 KiB slices

    const int blk  = blockIdx.x;       // b*4 + c
    const int b    = blk >> 2;
    const int c    = blk & (NCHK - 1);
    const int tid  = threadIdx.x;
    const int lane = tid & 63;
    const int wave = tid >> 6;

    float4* slice = lds4 + wave * 256;

    const float DT = 1e-3f;
    const float cd00 = Cptr[0]*DT, cd01 = Cptr[1]*DT;
    const float cd10 = Cptr[2]*DT, cd11 = Cptr[3]*DT;
    const float i00 = 1.0f + Aptr[0]*DT, i01 = Aptr[1]*DT;
    const float i10 = Aptr[2]*DT,        i11 = 1.0f + Aptr[3]*DT;

    const int wbase = b * T_ + c * CSTEP + wave * 512;      // step index
    const float4* xw = (const float4*)xic + wbase;
    const float4* dw = (const float4*)dy  + (wbase >> 1);
    float4*       ow = out4 + (wbase >> 1);

    // ---------------- phase A ----------------
    // xic loads + transpose first (t dies before dy staging -> lower peak VGPR)
    float4 a[LPT];
    {
        float4 t[8];
        #pragma unroll
        for (int j = 0; j < 8; ++j) t[j] = xw[j*64 + lane];
        #pragma unroll
        for (int rr = 0; rr < 2; ++rr) {
            #pragma unroll
            for (int jj = 0; jj < 4; ++jj) {
                int j = 4*rr + jj;
                int f = j*64 + lane;
                int rel = (f >> 3) & 31;
                slice[rel*8 + ((lane & 7) ^ (rel & 7))] = t[j];
            }
            if ((lane >> 5) == rr) {
                int rel = lane & 31;
                #pragma unroll
                for (int s = 0; s < LPT; ++s)
                    a[s] = slice[rel*8 + (s ^ (rel & 7))];
            }
        }
    }

    Aff S;
    {
        // dy load + transpose (scoped: u,d die after compose)
        float4 u[4];
        #pragma unroll
        for (int j = 0; j < 4; ++j) u[j] = dw[j*64 + lane];
        #pragma unroll
        for (int j = 0; j < 4; ++j) {
            int f = j*64 + lane;
            int o = f >> 2;
            slice[o*4 + ((f & 3) ^ ((o >> 1) & 3))] = u[j];
        }
        float4 d[4];
        #pragma unroll
        for (int s = 0; s < 4; ++s)
            d[s] = slice[lane*4 + (s ^ ((lane >> 1) & 3))];

        // thread-local compose
        Aff P;
        STEP_MAP(0, P);
        #pragma unroll
        for (int i = 1; i < LPT; ++i) { Aff s; STEP_MAP(i, s); P = aff_compose(s, P); }

        // wave Kogge-Stone inclusive scan
        S = P;
        #pragma unroll
        for (int sh = 1; sh < 64; sh <<= 1) {
            Aff q;
            q.m00 = __shfl_up(S.m00, sh); q.m01 = __shfl_up(S.m01, sh);
            q.m10 = __shfl_up(S.m10, sh); q.m11 = __shfl_up(S.m11, sh);
            q.v0  = __shfl_up(S.v0,  sh); q.v1  = __shfl_up(S.v1,  sh);
            if (lane >= sh) S = aff_compose(S, q);
        }
    }

    // wave totals -> slice headers
    if (lane == 63) {
        float* h = (float*)slice;
        h[0] = S.m00; h[1] = S.m01; h[2] = S.m10; h[3] = S.m11;
        h[4] = S.v0;  h[5] = S.v1;
    }
    __syncthreads();

    // wave-exclusive prefix within block (<=3 composes)
    Aff Ew = aff_identity();
    for (int w = 0; w < wave; ++w) {
        const float* h = (const float*)(lds4 + w * 256);
        Aff t2;
        t2.m00 = h[0]; t2.m01 = h[1]; t2.m10 = h[2]; t2.m11 = h[3];
        t2.v0  = h[4]; t2.v1  = h[5];
        Ew = aff_compose(t2, Ew);
    }

    // thread 0: block total -> ws
    if (tid == 0) {
        Aff Tb = aff_identity();
        #pragma unroll
        for (int w = 0; w < 4; ++w) {
            const float* h = (const float*)(lds4 + w * 256);
            Aff t2;
            t2.m00 = h[0]; t2.m01 = h[1]; t2.m10 = h[2]; t2.m11 = h[3];
            t2.v0  = h[4]; t2.v1  = h[5];
            Tb = aff_compose(t2, Tb);
        }
        float* o = totals + (size_t)blk * 6;
        o[0] = Tb.m00; o[1] = Tb.m01; o[2] = Tb.m10; o[3] = Tb.m11;
        o[4] = Tb.v0;  o[5] = Tb.v1;
    }

    // lane-exclusive prefix within wave; E = block-exclusive prefix
    Aff E;
    {
        Aff El;
        El.m00 = __shfl_up(S.m00, 1); El.m01 = __shfl_up(S.m01, 1);
        El.m10 = __shfl_up(S.m10, 1); El.m11 = __shfl_up(S.m11, 1);
        El.v0  = __shfl_up(S.v0,  1); El.v1  = __shfl_up(S.v1,  1);
        if (lane == 0) El = aff_identity();
        E = aff_compose(El, Ew);
    }

    // ---------------- grid-wide sync ----------------
    cg::this_grid().sync();

    // ---------------- phase B ----------------
    // carry-in state: R7-K2's exact sequential arithmetic (broadcast loads)
    float xb0 = 1.0f, xb1 = 0.0f;
    for (int w = 0; w < c; ++w) {
        const float* h = totals + ((size_t)(b * NCHK + w)) * 6;
        float nx0 = h[0]*xb0 + h[1]*xb1 + h[4];
        float nx1 = h[2]*xb0 + h[3]*xb1 + h[5];
        xb0 = nx0; xb1 = nx1;
    }

    float x0 = E.m00*xb0 + E.m01*xb1 + E.v0;
    float x1 = E.m10*xb0 + E.m11*xb1 + E.v1;

    // re-load dy (L3-warm) + transpose (slice safe: grid.sync passed)
    float4 d[4];
    {
        float4 u[4];
        #pragma unroll
        for (int j = 0; j < 4; ++j) u[j] = dw[j*64 + lane];
        #pragma unroll
        for (int j = 0; j < 4; ++j) {
            int f = j*64 + lane;
            int o = f >> 2;
            slice[o*4 + ((f & 3) ^ ((o >> 1) & 3))] = u[j];
        }
        #pragma unroll
        for (int s = 0; s < 4; ++s)
            d[s] = slice[lane*4 + (s ^ ((lane >> 1) & 3))];
    }

    // replay from registers
    float4 o4[4];
    #pragma unroll
    for (int i = 0; i < LPT; ++i) {
        float oxx = cd00*x0 + cd01*x1;
        float oyy = cd10*x0 + cd11*x1;
        if (i & 1) { o4[i>>1].z = oxx; o4[i>>1].w = oyy; }
        else       { o4[i>>1].x = oxx; o4[i>>1].y = oyy; }
        Aff s; STEP_MAP(i, s);
        float nx0 = s.m00*x0 + s.m01*x1 + s.v0;
        float nx1 = s.m10*x0 + s.m11*x1 + s.v1;
        x0 = nx0; x1 = nx1;
    }

    // out transpose, coalesced stores
    #pragma unroll
    for (int s = 0; s < 4; ++s)
        slice[lane*4 + (s ^ ((lane >> 1) & 3))] = o4[s];
    #pragma unroll
    for (int j = 0; j < 4; ++j) {
        int f = j*64 + lane;
        int o = f >> 2;
        ow[f] = slice[o*4 + ((f & 3) ^ ((o >> 1) & 3))];
    }
}

// ======================= R7 fallback path (proven) =======================
__global__ __launch_bounds__(NT) void grm_tot(
    const float* __restrict__ xic, const float* __restrict__ dy,
    const float* __restrict__ Aptr, const float* __restrict__ Cptr,
    float* __restrict__ totals)           // [B][3][6]
{
    __shared__ float4 lds4[4 * 256];

    const int blk  = blockIdx.x;
    const int b    = blk / 3;
    const int c    = blk - b * 3;
    const int tid  = threadIdx.x;
    const int lane = tid & 63;
    const int wave = tid >> 6;
    float4* slice = lds4 + wave * 256;

    const float DT = 1e-3f;
    const float cd00 = Cptr[0]*DT, cd01 = Cptr[1]*DT;
    const float cd10 = Cptr[2]*DT, cd11 = Cptr[3]*DT;
    const float i00 = 1.0f + Aptr[0]*DT, i01 = Aptr[1]*DT;
    const float i10 = Aptr[2]*DT,        i11 = 1.0f + Aptr[3]*DT;

    const int wbase = b * T_ + c * CSTEP + wave * 512;
    const float4* xw = (const float4*)xic + wbase;
    const float4* dw = (const float4*)dy  + (wbase >> 1);

    float4 t[8], u[4];
    #pragma unroll
    for (int j = 0; j < 8; ++j) t[j] = xw[j*64 + lane];
    #pragma unroll
    for (int j = 0; j < 4; ++j) u[j] = dw[j*64 + lane];

    float4 a[LPT];
    #pragma unroll
    for (int rr = 0; rr < 2; ++rr) {
        #pragma unroll
        for (int jj = 0; jj < 4; ++jj) {
            int j = 4*rr + jj;
            int f = j*64 + lane;
            int rel = (f >> 3) & 31;
            slice[rel*8 + ((lane & 7) ^ (rel & 7))] = t[j];
        }
        if ((lane >> 5) == rr) {
            int rel = lane & 31;
            #pragma unroll
            for (int s = 0; s < LPT; ++s)
                a[s] = slice[rel*8 + (s ^ (rel & 7))];
        }
    }

    #pragma unroll
    for (int j = 0; j < 4; ++j) {
        int f = j*64 + lane;
        int o = f >> 2;
        slice[o*4 + ((f & 3) ^ ((o >> 1) & 3))] = u[j];
    }
    float4 d[4];
    #pragma unroll
    for (int s = 0; s < 4; ++s)
        d[s] = slice[lane*4 + (s ^ ((lane >> 1) & 3))];

    Aff P;
    STEP_MAP(0, P);
    #pragma unroll
    for (int i = 1; i < LPT; ++i) { Aff s; STEP_MAP(i, s); P = aff_compose(s, P); }

    Aff S = P;
    #pragma unroll
    for (int sh = 1; sh < 64; sh <<= 1) {
        Aff q;
        q.m00 = __shfl_up(S.m00, sh); q.m01 = __shfl_up(S.m01, sh);
        q.m10 = __shfl_up(S.m10, sh); q.m11 = __shfl_up(S.m11, sh);
        q.v0  = __shfl_up(S.v0,  sh); q.v1  = __shfl_up(S.v1,  sh);
        if (lane >= sh) S = aff_compose(S, q);
    }

    if (lane == 63) {
        float* h = (float*)slice;
        h[0] = S.m00; h[1] = S.m01; h[2] = S.m10; h[3] = S.m11;
        h[4] = S.v0;  h[5] = S.v1;
    }
    __syncthreads();

    if (tid == 0) {
        Aff Tb = aff_identity();
        #pragma unroll
        for (int w = 0; w < 4; ++w) {
            const float* h = (const float*)(lds4 + w * 256);
            Aff t2;
            t2.m00 = h[0]; t2.m01 = h[1]; t2.m10 = h[2]; t2.m11 = h[3];
            t2.v0  = h[4]; t2.v1  = h[5];
            Tb = aff_compose(t2, Tb);
        }
        float* o = totals + (size_t)blk * 6;
        o[0] = Tb.m00; o[1] = Tb.m01; o[2] = Tb.m10; o[3] = Tb.m11;
        o[4] = Tb.v0;  o[5] = Tb.v1;
    }
}

__global__ __launch_bounds__(NT) void grm_xs(
    const float* __restrict__ totals,     // [B][3][6]
    float2* __restrict__ xs)              // [B][4]
{
    const int b = blockIdx.x * NT + threadIdx.x;
    float x0 = 1.0f, x1 = 0.0f;
    float2* xb = xs + (size_t)b * NCHK;
    xb[0] = make_float2(x0, x1);
    for (int c = 0; c < NCHK - 1; ++c) {
        const float* h = totals + ((size_t)b * 3 + c) * 6;
        float nx0 = h[0]*x0 + h[1]*x1 + h[4];
        float nx1 = h[2]*x0 + h[3]*x1 + h[5];
        x0 = nx0; x1 = nx1;
        xb[c + 1] = make_float2(x0, x1);
    }
}

__global__ __launch_bounds__(NT) void grm_emit(
    const float* __restrict__ xic, const float* __restrict__ dy,
    const float* __restrict__ Aptr, const float* __restrict__ Cptr,
    const float2* __restrict__ xs,        // [B][4]
    float4* __restrict__ out4)
{
    __shared__ float4 lds4[4 * 256];

    const int blk  = blockIdx.x;
    const int b    = blk >> 2;
    const int c    = blk & (NCHK - 1);
    const int tid  = threadIdx.x;
    const int lane = tid & 63;
    const int wave = tid >> 6;
    float4* slice = lds4 + wave * 256;

    const float DT = 1e-3f;
    const float cd00 = Cptr[0]*DT, cd01 = Cptr[1]*DT;
    const float cd10 = Cptr[2]*DT, cd11 = Cptr[3]*DT;
    const float i00 = 1.0f + Aptr[0]*DT, i01 = Aptr[1]*DT;
    const float i10 = Aptr[2]*DT,        i11 = 1.0f + Aptr[3]*DT;

    const float2 xbv = xs[blk];
    const float xb0 = xbv.x, xb1 = xbv.y;

    const int wbase = b * T_ + c * CSTEP + wave * 512;
    const float4* xw = (const float4*)xic + wbase;
    const float4* dw = (const float4*)dy  + (wbase >> 1);
    float4*       ow = out4 + (wbase >> 1);

    float4 t[8], u[4];
    #pragma unroll
    for (int j = 0; j < 8; ++j) t[j] = xw[j*64 + lane];
    #pragma unroll
    for (int j = 0; j < 4; ++j) u[j] = dw[j*64 + lane];

    float4 a[LPT];
    #pragma unroll
    for (int rr = 0; rr < 2; ++rr) {
        #pragma unroll
        for (int jj = 0; jj < 4; ++jj) {
            int j = 4*rr + jj;
            int f = j*64 + lane;
            int rel = (f >> 3) & 31;
            slice[rel*8 + ((lane & 7) ^ (rel & 7))] = t[j];
        }
        if ((lane >> 5) == rr) {
            int rel = lane & 31;
            #pragma unroll
            for (int s = 0; s < LPT; ++s)
                a[s] = slice[rel*8 + (s ^ (rel & 7))];
        }
    }

    #pragma unroll
    for (int j = 0; j < 4; ++j) {
        int f = j*64 + lane;
        int o = f >> 2;
        slice[o*4 + ((f & 3) ^ ((o >> 1) & 3))] = u[j];
    }
    float4 d[4];
    #pragma unroll
    for (int s = 0; s < 4; ++s)
        d[s] = slice[lane*4 + (s ^ ((lane >> 1) & 3))];

    Aff P;
    STEP_MAP(0, P);
    #pragma unroll
    for (int i = 1; i < LPT; ++i) { Aff s; STEP_MAP(i, s); P = aff_compose(s, P); }

    Aff S = P;
    #pragma unroll
    for (int sh = 1; sh < 64; sh <<= 1) {
        Aff q;
        q.m00 = __shfl_up(S.m00, sh); q.m01 = __shfl_up(S.m01, sh);
        q.m10 = __shfl_up(S.m10, sh); q.m11 = __shfl_up(S.m11, sh);
        q.v0  = __shfl_up(S.v0,  sh); q.v1  = __shfl_up(S.v1,  sh);
        if (lane >= sh) S = aff_compose(S, q);
    }

    if (lane == 63) {
        float* h = (float*)slice;
        h[0] = S.m00; h[1] = S.m01; h[2] = S.m10; h[3] = S.m11;
        h[4] = S.v0;  h[5] = S.v1;
    }
    __syncthreads();

    Aff Ew = aff_identity();
    for (int w = 0; w < wave; ++w) {
        const float* h = (const float*)(lds4 + w * 256);
        Aff t2;
        t2.m00 = h[0]; t2.m01 = h[1]; t2.m10 = h[2]; t2.m11 = h[3];
        t2.v0  = h[4]; t2.v1  = h[5];
        Ew = aff_compose(t2, Ew);
    }

    Aff El;
    El.m00 = __shfl_up(S.m00, 1); El.m01 = __shfl_up(S.m01, 1);
    El.m10 = __shfl_up(S.m10, 1); El.m11 = __shfl_up(S.m11, 1);
    El.v0  = __shfl_up(S.v0,  1); El.v1  = __shfl_up(S.v1,  1);
    if (lane == 0) El = aff_identity();
    Aff E = aff_compose(El, Ew);

    __syncthreads();

    float x0 = E.m00*xb0 + E.m01*xb1 + E.v0;
    float x1 = E.m10*xb0 + E.m11*xb1 + E.v1;

    float4 o4[4];
    #pragma unroll
    for (int i = 0; i < LPT; ++i) {
        float oxx = cd00*x0 + cd01*x1;
        float oyy = cd10*x0 + cd11*x1;
        if (i & 1) { o4[i>>1].z = oxx; o4[i>>1].w = oyy; }
        else       { o4[i>>1].x = oxx; o4[i>>1].y = oyy; }
        Aff s; STEP_MAP(i, s);
        float nx0 = s.m00*x0 + s.m01*x1 + s.v0;
        float nx1 = s.m10*x0 + s.m11*x1 + s.v1;
        x0 = nx0; x1 = nx1;
    }

    #pragma unroll
    for (int s = 0; s < 4; ++s)
        slice[lane*4 + (s ^ ((lane >> 1) & 3))] = o4[s];
    #pragma unroll
    for (int j = 0; j < 4; ++j) {
        int f = j*64 + lane;
        int o = f >> 2;
        ow[f] = slice[o*4 + ((f & 3) ^ ((o >> 1) & 3))];
    }
}

extern "C" void kernel_launch(void* const* d_in, const int* in_sizes, int n_in,
                              void* d_out, int out_size, void* d_ws, size_t ws_size,
                              hipStream_t stream) {
    const float* xic  = (const float*)d_in[0];   // [B,T,2,2]
    const float* dy   = (const float*)d_in[1];   // [B,T,2]
    const float* Aptr = (const float*)d_in[2];   // [2,2]
    const float* Cptr = (const float*)d_in[3];   // [2,2]
    float4* out = (float4*)d_out;                // [B,T,2]

    // Deterministic co-residency check (same result every call; the chosen
    // launch path is therefore identical across calls — graph-capture safe).
    int nb = 0;
    hipError_t qe = hipOccupancyMaxActiveBlocksPerMultiprocessor(&nb, grm_coop, NT, 0);
    const bool coop_ok = (qe == hipSuccess) && (nb >= 8);

    if (coop_ok) {
        // ws: totals [NBLK][6] floats = 48 KiB, fully written in phase A.
        float* totals = (float*)d_ws;
        void* args[] = { (void*)&xic, (void*)&dy, (void*)&Aptr, (void*)&Cptr,
                         (void*)&totals, (void*)&out };
        hipLaunchCooperativeKernel((void*)grm_coop, dim3(NBLK), dim3(NT),
                                   args, 0, stream);
    } else {
        // R7 fallback: totals at ws+0 ([B][3][6], 36 KiB), xs at ws+40960.
        char* ws = (char*)d_ws;
        float*  totals = (float*)ws;
        float2* xs     = (float2*)(ws + 40960);
        grm_tot <<<B_ * 3,    NT, 0, stream>>>(xic, dy, Aptr, Cptr, totals);
        grm_xs  <<<B_ / NT,   NT, 0, stream>>>(totals, xs);
        grm_emit<<<B_ * NCHK, NT, 0, stream>>>(xic, dy, Aptr, Cptr, xs, out);
    }
}